// Round 1
// 307.085 us; speedup vs baseline: 1.2979x; 1.2979x over previous
//
#include <hip/hip_runtime.h>
#include <math.h>

#define B 2
#define T 4096
#define D 1024
#define DH 32
#define TNB 32        // 128-row tiles per batch
#define NBLK 528      // TNB*(TNB+1)/2 causal tile pairs
#define NK 12         // per-chunk candidates kept (safety margin over 8)
#define CPR (32*NK)   // candidates per row = 384

typedef __bf16 bf16x8 __attribute__((ext_vector_type(8)));
typedef float f32x4 __attribute__((ext_vector_type(4)));

#define AS1 __attribute__((address_space(1)))
#define AS3 __attribute__((address_space(3)))

// monotone f32 -> u32 (order-preserving); branchless
__device__ __forceinline__ unsigned mono32(float v) {
    unsigned u = __float_as_uint(v);
    u ^= ((unsigned)((int)u >> 31)) | 0x80000000u;
    return u;
}
__device__ __forceinline__ float unmono32(unsigned u) {
    u ^= ((unsigned)((int)(~u) >> 31)) | 0x80000000u;
    return __uint_as_float(u);
}

// ---------------- K_conv: src -> (hi, lo) bf16 split (2048 elems/block) -------
__global__ __launch_bounds__(256) void conv_kernel(const float* __restrict__ x,
        __bf16* __restrict__ xhi, __bf16* __restrict__ xlo)
{
    int i = (blockIdx.x * 256 + threadIdx.x) << 3;     // 8 floats/thread
    float4 a = *(const float4*)(x + i);
    float4 c = *(const float4*)(x + i + 4);
    float av[8] = {a.x, a.y, a.z, a.w, c.x, c.y, c.z, c.w};
    __bf16 h[8], l[8];
    #pragma unroll
    for (int j = 0; j < 8; ++j) {
        h[j] = (__bf16)av[j];
        l[j] = (__bf16)(av[j] - (float)h[j]);
    }
    *(float4*)(xhi + i) = *(float4*)h;
    *(float4*)(xlo + i) = *(float4*)l;
}

// ---------------- K0: per-batch column sums (for the t=0 row) ----------------
__global__ void mean_kernel(const float* __restrict__ x, float* __restrict__ meansum)
{
    int gid  = blockIdx.x;           // B * 4 dblk * 16 tch = 128 blocks
    int b    = gid >> 6;
    int rem  = gid & 63;
    int dblk = rem >> 4;
    int tch  = rem & 15;
    int d = dblk * 256 + threadIdx.x;
    const float* xp = x + (b * T + tch * 256) * D + d;
    float s = 0.f;
    #pragma unroll 8
    for (int it = 0; it < 256; ++it) s += xp[it * D];
    atomicAdd(&meansum[(b << 10) + d], s);
}

// ---------------- K1: q/k projection as split-bf16 MFMA GEMM -----------------
__global__ __launch_bounds__(256) void qk_mfma_kernel(
        const __bf16* __restrict__ xhi, const __bf16* __restrict__ xlo,
        const __bf16* __restrict__ Whi, const __bf16* __restrict__ Wlo,
        float* __restrict__ qo, float* __restrict__ ko)
{
    __shared__ __align__(16) __bf16 stg[15360];
    __bf16* sAhi = stg;            // 128 x 40
    __bf16* sAlo = stg + 5120;
    __bf16* sBhi = stg + 10240;    // 64 x 40
    __bf16* sBlo = stg + 12800;

    int tid = threadIdx.x;
    int m0 = blockIdx.x << 7;
    int w = tid >> 6, lane = tid & 63;
    int fr = lane & 15, fq = lane >> 4;

    int arow = tid >> 1, ah = tid & 1;      // A staging: 2 chunks of 16 bf16
    int brow = tid >> 2, bq = tid & 3;      // B staging: 4 chunks of 8 bf16

    const __bf16* gAh = xhi + (size_t)(m0 + arow) * D + ah * 16;
    const __bf16* gAl = xlo + (size_t)(m0 + arow) * D + ah * 16;
    const __bf16* gBh = Whi + brow * D + bq * 8;
    const __bf16* gBl = Wlo + brow * D + bq * 8;

    f32x4 acc[2][4];
    #pragma unroll
    for (int i = 0; i < 2; ++i)
        #pragma unroll
        for (int j = 0; j < 4; ++j) acc[i][j] = (f32x4){0.f, 0.f, 0.f, 0.f};

    float4 a0 = *(const float4*)(gAh);
    float4 a1 = *(const float4*)(gAh + 8);
    float4 a2 = *(const float4*)(gAl);
    float4 a3 = *(const float4*)(gAl + 8);
    float4 b0 = *(const float4*)(gBh);
    float4 b1 = *(const float4*)(gBl);

    int sa = arow * 40 + ah * 16;
    int sb = brow * 40 + bq * 8;

    for (int kc = 0; kc < 32; ++kc) {
        __syncthreads();
        *(float4*)(sAhi + sa) = a0;  *(float4*)(sAhi + sa + 8) = a1;
        *(float4*)(sAlo + sa) = a2;  *(float4*)(sAlo + sa + 8) = a3;
        *(float4*)(sBhi + sb) = b0;  *(float4*)(sBlo + sb) = b1;
        __syncthreads();
        if (kc + 1 < 32) {
            int k0 = (kc + 1) << 5;
            a0 = *(const float4*)(gAh + k0);
            a1 = *(const float4*)(gAh + k0 + 8);
            a2 = *(const float4*)(gAl + k0);
            a3 = *(const float4*)(gAl + k0 + 8);
            b0 = *(const float4*)(gBh + k0);
            b1 = *(const float4*)(gBl + k0);
        }
        bf16x8 fah[2], fal[2], fbh[4], fbl[4];
        #pragma unroll
        for (int i = 0; i < 2; ++i) {
            int r = (w << 5) + i * 16 + fr;
            fah[i] = *(const bf16x8*)(sAhi + r * 40 + fq * 8);
            fal[i] = *(const bf16x8*)(sAlo + r * 40 + fq * 8);
        }
        #pragma unroll
        for (int j = 0; j < 4; ++j) {
            int r = j * 16 + fr;
            fbh[j] = *(const bf16x8*)(sBhi + r * 40 + fq * 8);
            fbl[j] = *(const bf16x8*)(sBlo + r * 40 + fq * 8);
        }
        #pragma unroll
        for (int i = 0; i < 2; ++i)
            #pragma unroll
            for (int j = 0; j < 4; ++j) {
                acc[i][j] = __builtin_amdgcn_mfma_f32_16x16x32_bf16(fah[i], fbh[j], acc[i][j], 0, 0, 0);
                acc[i][j] = __builtin_amdgcn_mfma_f32_16x16x32_bf16(fah[i], fbl[j], acc[i][j], 0, 0, 0);
                acc[i][j] = __builtin_amdgcn_mfma_f32_16x16x32_bf16(fal[i], fbh[j], acc[i][j], 0, 0, 0);
            }
    }
    // writeout: C layout col=lane&15, row=fq*4+reg
    #pragma unroll
    for (int i = 0; i < 2; ++i) {
        int grow0 = m0 + (w << 5) + i * 16 + (fq << 2);
        #pragma unroll
        for (int j = 0; j < 4; ++j) {
            int gn = j * 16 + fr;
            float* dst = (gn < 32) ? (qo + grow0 * DH + gn)
                                   : (ko + grow0 * DH + gn - 32);
            dst[0]      = acc[i][j][0];
            dst[DH]     = acc[i][j][1];
            dst[2 * DH] = acc[i][j][2];
            dst[3 * DH] = acc[i][j][3];
        }
    }
}

// ---------------- K2: hi-only bf16 MFMA sim GEMM + per-row top-12 per 128-col chunk
// Async double-buffered staging via global_load_lds (16 B/lane, wave-uniform
// base + lane*16). LDS dest stays LINEAR (rule #21); bank-conflict-free frag
// reads achieved by pre-swizzling the per-lane GLOBAL source 16B-slot
// (slot ^= (row>>1)&3) and applying the same XOR on the ds_read offset.
// Scan phase: register-resident branchless top-12 via sorted packed-key
// insertion chain (NO runtime-indexed arrays -> no scratch).
__global__ __launch_bounds__(256, 4) void topk_mfma_kernel(
        const __bf16* __restrict__ xhi,
        float* __restrict__ pvals, int* __restrict__ pidx)
{
    __shared__ __align__(16) float Sbuf[64 * 129];     // 33024 B; staging aliases
    __bf16* stg = (__bf16*)Sbuf;
    // buf layout (bf16 units): A0 @0 (4096), B0 @4096, A1 @8192, B1 @12288

    int tid = threadIdx.x;
    int b = blockIdx.x / NBLK;
    int l = blockIdx.x - b * NBLK;
    int rt = (int)((sqrtf(8.f * l + 1.f) - 1.f) * 0.5f);
    while ((rt + 1) * (rt + 2) / 2 <= l) ++rt;
    while (rt * (rt + 1) / 2 > l) --rt;
    int ct = l - rt * (rt + 1) / 2;
    int r0 = rt << 7, c0 = ct << 7;
    int base = b * T;

    int w = tid >> 6, lane = tid & 63;
    int wr = (w >> 1) << 6, wc = (w & 1) << 6;
    bool active = !(rt == ct && w == 1);   // diag block, fully non-causal quadrant
    int fr = lane & 15, fq = lane >> 4;    // fragment: row-in-tile, k-quad
    // swizzled 16B-slot for frag reads: slot = fq ^ ((row>>1)&3); row parity
    // within a frag group depends only on fr (bases are mult of 16)
    int fqs = (fq ^ ((fr >> 1) & 3)) << 3;          // bf16 offset

    // staging: lane i of wave w covers (row 16w + (i>>2), swizzled 16B-chunk)
    int lrow = lane >> 2;
    int lcq = (((lane & 3) ^ ((lane >> 3) & 3)) << 3);   // pre-swizzled source slot
    const __bf16* gA = xhi + (size_t)(base + r0) * D;
    const __bf16* gB = xhi + (size_t)(base + c0) * D;
    // per-lane global row offsets (A/B, halves 0/1)
    const __bf16* gA0 = gA + (size_t)((w << 4) + lrow) * D + lcq;
    const __bf16* gA1 = gA0 + (size_t)64 * D;
    const __bf16* gB0 = gB + (size_t)((w << 4) + lrow) * D + lcq;
    const __bf16* gB1 = gB0 + (size_t)64 * D;

    f32x4 acc[4][4];
    #pragma unroll
    for (int i = 0; i < 4; ++i)
        #pragma unroll
        for (int j = 0; j < 4; ++j) acc[i][j] = (f32x4){0.f, 0.f, 0.f, 0.f};

    // issue tile 0 into buf0
    {
        __bf16* bA = stg;           // buf0
        __bf16* bB = stg + 4096;
        __builtin_amdgcn_global_load_lds((const AS1 unsigned int*)(gA0),
            (AS3 unsigned int*)(bA + (w << 9)), 16, 0, 0);
        __builtin_amdgcn_global_load_lds((const AS1 unsigned int*)(gA1),
            (AS3 unsigned int*)(bA + 2048 + (w << 9)), 16, 0, 0);
        __builtin_amdgcn_global_load_lds((const AS1 unsigned int*)(gB0),
            (AS3 unsigned int*)(bB + (w << 9)), 16, 0, 0);
        __builtin_amdgcn_global_load_lds((const AS1 unsigned int*)(gB1),
            (AS3 unsigned int*)(bB + 2048 + (w << 9)), 16, 0, 0);
    }

    for (int kc = 0; kc < 32; ++kc) {
        __syncthreads();                   // tile kc resident in buf[kc&1]
        if (kc + 1 < 32) {                 // DMA tile kc+1 into the other buffer
            int ko = (kc + 1) << 5;
            __bf16* bA = stg + (((kc + 1) & 1) << 13);
            __bf16* bB = bA + 4096;
            __builtin_amdgcn_global_load_lds((const AS1 unsigned int*)(gA0 + ko),
                (AS3 unsigned int*)(bA + (w << 9)), 16, 0, 0);
            __builtin_amdgcn_global_load_lds((const AS1 unsigned int*)(gA1 + ko),
                (AS3 unsigned int*)(bA + 2048 + (w << 9)), 16, 0, 0);
            __builtin_amdgcn_global_load_lds((const AS1 unsigned int*)(gB0 + ko),
                (AS3 unsigned int*)(bB + (w << 9)), 16, 0, 0);
            __builtin_amdgcn_global_load_lds((const AS1 unsigned int*)(gB1 + ko),
                (AS3 unsigned int*)(bB + 2048 + (w << 9)), 16, 0, 0);
        }
        if (active) {
            const __bf16* cA = stg + ((kc & 1) << 13);
            const __bf16* cB = cA + 4096;
            bf16x8 ah[4], bh[4];
            #pragma unroll
            for (int i = 0; i < 4; ++i) {
                int ar = wr + i * 16 + fr;
                ah[i] = *(const bf16x8*)(cA + ar * 32 + fqs);
                int bc = wc + i * 16 + fr;
                bh[i] = *(const bf16x8*)(cB + bc * 32 + fqs);
            }
            #pragma unroll
            for (int i = 0; i < 4; ++i)
                #pragma unroll
                for (int j = 0; j < 4; ++j)
                    acc[i][j] = __builtin_amdgcn_mfma_f32_16x16x32_bf16(ah[i], bh[j], acc[i][j], 0, 0, 0);
        }
    }

    int cr = fq << 2, cc = fr;             // C layout: col=lane&15, row=fq*4+reg
    #pragma unroll
    for (int phase = 0; phase < 2; ++phase) {
        __syncthreads();                   // staging reads / prior scan done
        if ((w >> 1) == phase) {           // waves owning rows [phase*64, +64)
            #pragma unroll
            for (int i = 0; i < 4; ++i)
                #pragma unroll
                for (int j = 0; j < 4; ++j) {
                    float* sp = Sbuf + (i * 16 + cr) * 129 + wc + j * 16 + cc;
                    sp[0]       = acc[i][j][0];
                    sp[129]     = acc[i][j][1];
                    sp[2 * 129] = acc[i][j][2];
                    sp[3 * 129] = acc[i][j][3];
                }
        }
        __syncthreads();
        if (tid < 64) {                    // per-row top-12, register-resident
            int gt = r0 + (phase << 6) + tid;
            int cmax = gt - c0;
            if (cmax > 128) cmax = 128;
            if (cmax < 0) cmax = 0;
            // sorted-descending packed keys: (mono(v) & ~127) | (127 - col)
            // larger key = larger value; ties -> earlier column (matches ref)
            unsigned key[NK];
            #pragma unroll
            for (int i = 0; i < NK; ++i) key[i] = 0u;   // 0 == invalid
            const float* Srow = Sbuf + tid * 129;
            for (int cb = 0; cb < cmax; cb += 8) {
                float v[8];
                #pragma unroll
                for (int j = 0; j < 8; ++j) v[j] = Srow[cb + j];   // 8 loads in flight
                #pragma unroll
                for (int j = 0; j < 8; ++j) {
                    int c = cb + j;
                    unsigned u = mono32(v[j]);
                    unsigned t = (c < cmax) ? ((u & 0xFFFFFF80u) | (unsigned)(127 - c)) : 0u;
                    #pragma unroll
                    for (int i = 0; i < NK; ++i) {      // branchless sorted insert
                        unsigned hi = (key[i] > t) ? key[i] : t;   // v_max_u32
                        unsigned lo = (key[i] > t) ? t : key[i];   // v_min_u32
                        key[i] = hi; t = lo;
                    }
                }
            }
            int ob = (base + gt) * CPR + ct * NK;
            #pragma unroll
            for (int i = 0; i < NK; ++i) {
                unsigned kk = key[i];
                bool vld = kk != 0u;
                float dv = unmono32(kk & 0xFFFFFF80u);
                pvals[ob + i] = vld ? dv : -INFINITY;
                pidx[ob + i]  = vld ? (c0 + 127 - (int)(kk & 127u)) : -1;
            }
        }
    }
}

// ---------------- K3: FUSED wave-per-row selection + message + gelu ----------
// Top-8 extraction rewritten with u64 packed keys (exact 32-bit value order,
// tie-break lower index) + static CAS chain + cndmask-tree lane select:
// no runtime-indexed arrays -> no scratch.
__global__ __launch_bounds__(256) void select_msg_kernel(const float* __restrict__ x,
        const float* __restrict__ q, const float* __restrict__ k,
        const float* __restrict__ meansum,
        const float* __restrict__ pvals, const int* __restrict__ pidx,
        const float* __restrict__ gain, const float* __restrict__ bias,
        const float* __restrict__ plm, const float* __restrict__ pls,
        float* __restrict__ out)
{
    int tid = threadIdx.x;
    int w = tid >> 6, lane = tid & 63;
    int rid = (blockIdx.x << 2) + w;         // global row b*T+t
    int b = rid >> 12, t = rid & (T - 1);
    int ncand = NK * ((t + 127) >> 7);

    // candidate loads (all in flight)
    float cv[6]; int ci[6];
    #pragma unroll
    for (int u = 0; u < 6; ++u) {
        int cid = lane + (u << 6);
        bool val = cid < ncand;
        cv[u] = val ? pvals[(size_t)rid * CPR + cid] : -INFINITY;
        ci[u] = val ? pidx[(size_t)rid * CPR + cid] : -1;
    }
    // prefetch xt fragments (independent of merge)
    const float* xt = x + (size_t)rid * D;
    float4 xt4[4];
    #pragma unroll
    for (int c = 0; c < 4; ++c)
        xt4[c] = *(const float4*)(xt + (c << 8) + (lane << 2));

    // butterfly merge -> approx top-12 (identical logic/tie-breaks)
    int si[NK];
    #pragma unroll
    for (int i = 0; i < NK; ++i) {
        float mv = cv[0]; int mi = ci[0];
        #pragma unroll
        for (int u = 1; u < 6; ++u)
            if (cv[u] > mv || (cv[u] == mv && ci[u] < mi)) { mv = cv[u]; mi = ci[u]; }
        #pragma unroll
        for (int off = 32; off >= 1; off >>= 1) {
            float ov = __shfl_xor(mv, off);
            int   oi = __shfl_xor(mi, off);
            if (ov > mv || (ov == mv && oi < mi)) { mv = ov; mi = oi; }
        }
        si[i] = mi;
        #pragma unroll
        for (int u = 0; u < 6; ++u)
            if (cv[u] == mv && ci[u] == mi) cv[u] = -INFINITY;
    }

    // exact fp32 re-rank: 4 batches of 3 candidates, loads batched in flight
    float ex[NK];
    #pragma unroll
    for (int batch = 0; batch < 4; ++batch) {
        float4 rv[3][4];
        #pragma unroll
        for (int s = 0; s < 3; ++s) {
            int i = batch * 3 + s;
            int sj = si[i];
            const float* xj = x + (size_t)((b << 12) + (sj >= 0 ? sj : 0)) * D;
            #pragma unroll
            for (int c = 0; c < 4; ++c)
                rv[s][c] = *(const float4*)(xj + (c << 8) + (lane << 2));
        }
        #pragma unroll
        for (int s = 0; s < 3; ++s) {
            float ss = 0.f;
            #pragma unroll
            for (int c = 0; c < 4; ++c)
                ss += xt4[c].x * rv[s][c].x + xt4[c].y * rv[s][c].y
                    + xt4[c].z * rv[s][c].z + xt4[c].w * rv[s][c].w;
            ex[batch * 3 + s] = ss;
        }
    }
    // shuffle-reduce all 12 (independent chains pipeline)
    #pragma unroll
    for (int i = 0; i < NK; ++i) {
        float ssum = ex[i];
        #pragma unroll
        for (int off = 32; off >= 1; off >>= 1) ssum += __shfl_xor(ssum, off);
        ex[i] = ssum;                       // validity tracked via si[i]
    }

    // exact top-8 via u64 packed keys: (mono(value) << 12) | (4095 - idx)
    // desc order, ties -> lower index (identical to old extraction order)
    unsigned long long top8[8];
    #pragma unroll
    for (int r = 0; r < 8; ++r) top8[r] = 0ull;
    #pragma unroll
    for (int i = 0; i < NK; ++i) {
        unsigned u = mono32(ex[i]);
        unsigned long long t64 = (si[i] >= 0)
            ? ((((unsigned long long)u) << 12) | (unsigned long long)(4095 - si[i]))
            : 0ull;
        #pragma unroll
        for (int r = 0; r < 8; ++r) {       // branchless sorted insert
            unsigned long long hi = (t64 > top8[r]) ? t64 : top8[r];
            unsigned long long lo = (t64 > top8[r]) ? top8[r] : t64;
            top8[r] = hi; t64 = lo;
        }
    }
    // static decode
    bool vld[8]; int bidx[8];
    #pragma unroll
    for (int i = 0; i < 8; ++i) {
        vld[i]  = top8[i] != 0ull;
        bidx[i] = 4095 - (int)(top8[i] & 4095ull);
    }

    // scores: lanes 8i..8i+7 compute dot(q[t], k[sel_i]); select key via
    // cndmask tree on i8 bits (no runtime array index)
    int i8 = lane >> 3, e = lane & 7;
    unsigned long long kk = (i8 & 4)
        ? ((i8 & 2) ? ((i8 & 1) ? top8[7] : top8[6]) : ((i8 & 1) ? top8[5] : top8[4]))
        : ((i8 & 2) ? ((i8 & 1) ? top8[3] : top8[2]) : ((i8 & 1) ? top8[1] : top8[0]));
    bool v8 = kk != 0ull;
    int g8 = v8 ? (4095 - (int)(kk & 4095ull)) : 0;
    float4 qv = *(const float4*)(q + (size_t)rid * DH + (e << 2));
    float4 kv = *(const float4*)(k + (size_t)((b << 12) + g8) * DH + (e << 2));
    float p = qv.x * kv.x + qv.y * kv.y + qv.z * kv.z + qv.w * kv.w;
    p += __shfl_xor(p, 1); p += __shfl_xor(p, 2); p += __shfl_xor(p, 4);
    p *= 0.17677669529663687f;               // 1/sqrt(32)

    float sc[8];
    #pragma unroll
    for (int i = 0; i < 8; ++i) sc[i] = __shfl(p, i << 3);

    float m = -INFINITY; int cnt = 0;
    #pragma unroll
    for (int i = 0; i < 8; ++i)
        if (vld[i]) { ++cnt; if (sc[i] > m) m = sc[i]; }

    float wgt[8]; float Z = 0.f; int gsel[8];
    #pragma unroll
    for (int i = 0; i < 8; ++i) {
        wgt[i] = vld[i] ? expf(sc[i] - m) : 0.f;
        Z += wgt[i];
        gsel[i] = vld[i] ? ((b << 12) + bidx[i]) : (b << 12);
    }
    float invZ = (cnt > 0) ? 1.f / Z : 0.f;
    #pragma unroll
    for (int i = 0; i < 8; ++i) wgt[i] *= invZ;

    // ---- fused epilogue: msg accumulation on lane's 16 dims + gelu ----
    float mix   = 1.f / (1.f + expf(-plm[0]));
    float scale = log1pf(expf(pls[0])) + 0.01f;
    const float onemix = 1.f - mix;

    float4 msg4[4];
    if (cnt == 0) {                          // t==0: uniform attention over ALL T
        #pragma unroll
        for (int c = 0; c < 4; ++c) {
            float4 ms = *(const float4*)(meansum + (b << 10) + (c << 8) + (lane << 2));
            msg4[c].x = ms.x * (1.f / (float)T); msg4[c].y = ms.y * (1.f / (float)T);
            msg4[c].z = ms.z * (1.f / (float)T); msg4[c].w = ms.w * (1.f / (float)T);
        }
    } else {
        #pragma unroll
        for (int c = 0; c < 4; ++c) msg4[c] = (float4){0.f, 0.f, 0.f, 0.f};
        #pragma unroll
        for (int g = 0; g < 2; ++g) {        // 2 batches of 4 rows (L2-hot re-read)
            float4 rv[4][4];
            #pragma unroll
            for (int s = 0; s < 4; ++s) {
                const float* xj = x + (size_t)gsel[g * 4 + s] * D;
                #pragma unroll
                for (int c = 0; c < 4; ++c)
                    rv[s][c] = *(const float4*)(xj + (c << 8) + (lane << 2));
            }
            #pragma unroll
            for (int s = 0; s < 4; ++s) {    // preserves i=0..7 summation order
                float wi = wgt[g * 4 + s];
                #pragma unroll
                for (int c = 0; c < 4; ++c) {
                    msg4[c].x += wi * rv[s][c].x; msg4[c].y += wi * rv[s][c].y;
                    msg4[c].z += wi * rv[s][c].z; msg4[c].w += wi * rv[s][c].w;
                }
            }
        }
    }
    #pragma unroll
    for (int c = 0; c < 4; ++c) {
        int d0 = (c << 8) + (lane << 2);
        float4 g4 = *(const float4*)(gain + d0);
        float4 b4 = *(const float4*)(bias + d0);
        float4 xv = xt4[c];
        float zi[4] = {
            (mix * xv.x + onemix * msg4[c].x) * g4.x + b4.x,
            (mix * xv.y + onemix * msg4[c].y) * g4.y + b4.y,
            (mix * xv.z + onemix * msg4[c].z) * g4.z + b4.z,
            (mix * xv.w + onemix * msg4[c].w) * g4.w + b4.w };
        float4 o4;
        o4.x = 0.5f * zi[0] * (1.f + erff(zi[0] * 0.70710678118654752f)) * scale;
        o4.y = 0.5f * zi[1] * (1.f + erff(zi[1] * 0.70710678118654752f)) * scale;
        o4.z = 0.5f * zi[2] * (1.f + erff(zi[2] * 0.70710678118654752f)) * scale;
        o4.w = 0.5f * zi[3] * (1.f + erff(zi[3] * 0.70710678118654752f)) * scale;
        *(float4*)(out + (size_t)rid * D + d0) = o4;
    }
}

extern "C" void kernel_launch(void* const* d_in, const int* in_sizes, int n_in,
                              void* d_out, int out_size, void* d_ws, size_t ws_size,
                              hipStream_t stream)
{
    const float* x    = (const float*)d_in[0];
    const float* Wq   = (const float*)d_in[1];
    const float* Wk   = (const float*)d_in[2];
    const float* gain = (const float*)d_in[3];
    const float* bias = (const float*)d_in[4];
    const float* plm  = (const float*)d_in[5];
    const float* pls  = (const float*)d_in[6];
    float* out = (float*)d_out;

    float* ws      = (float*)d_ws;
    float* q       = ws;                       // 262144
    float* k       = ws + 262144;              // 262144
    float* meansum = ws + 524288;              // 2048
    float* pvals   = ws + 526336;              // B*T*CPR = 3145728
    int*   pidx    = (int*)(ws + 3672064);     // 3145728
    __bf16* xhi    = (__bf16*)(ws + 6817792);  // B*T*D bf16 (4194304 float-slots)
    __bf16* xlo    = xhi + (size_t)B * T * D;
    __bf16* Whi    = xlo + (size_t)B * T * D;  // 64*1024 bf16
    __bf16* Wlo    = Whi + 64 * D;
    // total ws use: ~61 MB

    hipMemsetAsync(meansum, 0, 2048 * sizeof(float), stream);
    conv_kernel<<<B * T * D / 2048, 256, 0, stream>>>(x, xhi, xlo);
    conv_kernel<<<16, 256, 0, stream>>>(Wq, Whi, Wlo);
    conv_kernel<<<16, 256, 0, stream>>>(Wk, Whi + 32 * D, Wlo + 32 * D);
    mean_kernel<<<128, 256, 0, stream>>>(x, meansum);
    qk_mfma_kernel<<<B * T / 128, 256, 0, stream>>>(xhi, xlo, Whi, Wlo, q, k);
    topk_mfma_kernel<<<B * NBLK, 256, 0, stream>>>(xhi, pvals, pidx);
    select_msg_kernel<<<B * T / 4, 256, 0, stream>>>(x, q, k, meansum, pvals, pidx,
                                                     gain, bias, plm, pls, out);
}

// Round 2
// 284.145 us; speedup vs baseline: 1.4027x; 1.0807x over previous
//
#include <hip/hip_runtime.h>
#include <math.h>

#define B 2
#define T 4096
#define D 1024
#define DH 32
#define TNB 32        // 128-row tiles per batch
#define NBLK 528      // TNB*(TNB+1)/2 causal tile pairs
#define NK 12         // per-chunk candidates kept (safety margin over 8)
#define CPR (32*NK)   // candidates per row = 384

typedef __bf16 bf16x8 __attribute__((ext_vector_type(8)));
typedef float f32x4 __attribute__((ext_vector_type(4)));

#define AS1 __attribute__((address_space(1)))
#define AS3 __attribute__((address_space(3)))

// monotone f32 -> u32 (order-preserving); branchless
__device__ __forceinline__ unsigned mono32(float v) {
    unsigned u = __float_as_uint(v);
    u ^= ((unsigned)((int)u >> 31)) | 0x80000000u;
    return u;
}

// ---- wave-wide u32 max, result broadcast via readlane(63) (uniform/SGPR) ----
__device__ __forceinline__ unsigned dpp_umax_bcast(unsigned v) {
    #define DPPMAX(CTRL) { unsigned t_ = (unsigned)__builtin_amdgcn_update_dpp(0, (int)v, CTRL, 0xF, 0xF, true); v = v > t_ ? v : t_; }
    DPPMAX(0x111) DPPMAX(0x112) DPPMAX(0x114) DPPMAX(0x118)   // row_shr 1,2,4,8
    DPPMAX(0x142) DPPMAX(0x143)                               // row_bcast 15,31
    #undef DPPMAX
    return (unsigned)__builtin_amdgcn_readlane((int)v, 63);
}
// ---- wave-wide f32 sum, result broadcast via readlane(63) (uniform/SGPR) ----
__device__ __forceinline__ float dpp_fsum_bcast(float v) {
    #define DPPADD(CTRL) { int t_ = __builtin_amdgcn_update_dpp(0, __float_as_int(v), CTRL, 0xF, 0xF, true); v += __int_as_float(t_); }
    DPPADD(0x111) DPPADD(0x112) DPPADD(0x114) DPPADD(0x118)
    DPPADD(0x142) DPPADD(0x143)
    #undef DPPADD
    return __int_as_float(__builtin_amdgcn_readlane(__float_as_int(v), 63));
}
// ---- sum across each aligned 8-lane group (all lanes get the sum) ----
__device__ __forceinline__ float dpp_gsum8(float p) {
    { int t_ = __builtin_amdgcn_update_dpp(0, __float_as_int(p), 0x0B1, 0xF, 0xF, true); p += __int_as_float(t_); } // quad_perm xor1
    { int t_ = __builtin_amdgcn_update_dpp(0, __float_as_int(p), 0x04E, 0xF, 0xF, true); p += __int_as_float(t_); } // quad_perm xor2
    { int t_ = __builtin_amdgcn_update_dpp(0, __float_as_int(p), 0x141, 0xF, 0xF, true); p += __int_as_float(t_); } // row_half_mirror (xor7)
    return p;
}

// ---------------- K_conv: src -> (hi, lo) bf16 split (2048 elems/block) -------
__global__ __launch_bounds__(256) void conv_kernel(const float* __restrict__ x,
        __bf16* __restrict__ xhi, __bf16* __restrict__ xlo)
{
    int i = (blockIdx.x * 256 + threadIdx.x) << 3;     // 8 floats/thread
    float4 a = *(const float4*)(x + i);
    float4 c = *(const float4*)(x + i + 4);
    float av[8] = {a.x, a.y, a.z, a.w, c.x, c.y, c.z, c.w};
    __bf16 h[8], l[8];
    #pragma unroll
    for (int j = 0; j < 8; ++j) {
        h[j] = (__bf16)av[j];
        l[j] = (__bf16)(av[j] - (float)h[j]);
    }
    *(float4*)(xhi + i) = *(float4*)h;
    *(float4*)(xlo + i) = *(float4*)l;
}

// ---------------- K0: per-batch column sums (for the t=0 row) ----------------
__global__ void mean_kernel(const float* __restrict__ x, float* __restrict__ meansum)
{
    int gid  = blockIdx.x;           // B * 4 dblk * 16 tch = 128 blocks
    int b    = gid >> 6;
    int rem  = gid & 63;
    int dblk = rem >> 4;
    int tch  = rem & 15;
    int d = dblk * 256 + threadIdx.x;
    const float* xp = x + (b * T + tch * 256) * D + d;
    float s = 0.f;
    #pragma unroll 8
    for (int it = 0; it < 256; ++it) s += xp[it * D];
    atomicAdd(&meansum[(b << 10) + d], s);
}

// ---------------- K1: q/k projection as split-bf16 MFMA GEMM -----------------
__global__ __launch_bounds__(256) void qk_mfma_kernel(
        const __bf16* __restrict__ xhi, const __bf16* __restrict__ xlo,
        const __bf16* __restrict__ Whi, const __bf16* __restrict__ Wlo,
        float* __restrict__ qo, float* __restrict__ ko)
{
    __shared__ __align__(16) __bf16 stg[15360];
    __bf16* sAhi = stg;            // 128 x 40
    __bf16* sAlo = stg + 5120;
    __bf16* sBhi = stg + 10240;    // 64 x 40
    __bf16* sBlo = stg + 12800;

    int tid = threadIdx.x;
    int m0 = blockIdx.x << 7;
    int w = tid >> 6, lane = tid & 63;
    int fr = lane & 15, fq = lane >> 4;

    int arow = tid >> 1, ah = tid & 1;      // A staging: 2 chunks of 16 bf16
    int brow = tid >> 2, bq = tid & 3;      // B staging: 4 chunks of 8 bf16

    const __bf16* gAh = xhi + (size_t)(m0 + arow) * D + ah * 16;
    const __bf16* gAl = xlo + (size_t)(m0 + arow) * D + ah * 16;
    const __bf16* gBh = Whi + brow * D + bq * 8;
    const __bf16* gBl = Wlo + brow * D + bq * 8;

    f32x4 acc[2][4];
    #pragma unroll
    for (int i = 0; i < 2; ++i)
        #pragma unroll
        for (int j = 0; j < 4; ++j) acc[i][j] = (f32x4){0.f, 0.f, 0.f, 0.f};

    float4 a0 = *(const float4*)(gAh);
    float4 a1 = *(const float4*)(gAh + 8);
    float4 a2 = *(const float4*)(gAl);
    float4 a3 = *(const float4*)(gAl + 8);
    float4 b0 = *(const float4*)(gBh);
    float4 b1 = *(const float4*)(gBl);

    int sa = arow * 40 + ah * 16;
    int sb = brow * 40 + bq * 8;

    for (int kc = 0; kc < 32; ++kc) {
        __syncthreads();
        *(float4*)(sAhi + sa) = a0;  *(float4*)(sAhi + sa + 8) = a1;
        *(float4*)(sAlo + sa) = a2;  *(float4*)(sAlo + sa + 8) = a3;
        *(float4*)(sBhi + sb) = b0;  *(float4*)(sBlo + sb) = b1;
        __syncthreads();
        if (kc + 1 < 32) {
            int k0 = (kc + 1) << 5;
            a0 = *(const float4*)(gAh + k0);
            a1 = *(const float4*)(gAh + k0 + 8);
            a2 = *(const float4*)(gAl + k0);
            a3 = *(const float4*)(gAl + k0 + 8);
            b0 = *(const float4*)(gBh + k0);
            b1 = *(const float4*)(gBl + k0);
        }
        bf16x8 fah[2], fal[2], fbh[4], fbl[4];
        #pragma unroll
        for (int i = 0; i < 2; ++i) {
            int r = (w << 5) + i * 16 + fr;
            fah[i] = *(const bf16x8*)(sAhi + r * 40 + fq * 8);
            fal[i] = *(const bf16x8*)(sAlo + r * 40 + fq * 8);
        }
        #pragma unroll
        for (int j = 0; j < 4; ++j) {
            int r = j * 16 + fr;
            fbh[j] = *(const bf16x8*)(sBhi + r * 40 + fq * 8);
            fbl[j] = *(const bf16x8*)(sBlo + r * 40 + fq * 8);
        }
        #pragma unroll
        for (int i = 0; i < 2; ++i)
            #pragma unroll
            for (int j = 0; j < 4; ++j) {
                acc[i][j] = __builtin_amdgcn_mfma_f32_16x16x32_bf16(fah[i], fbh[j], acc[i][j], 0, 0, 0);
                acc[i][j] = __builtin_amdgcn_mfma_f32_16x16x32_bf16(fah[i], fbl[j], acc[i][j], 0, 0, 0);
                acc[i][j] = __builtin_amdgcn_mfma_f32_16x16x32_bf16(fal[i], fbh[j], acc[i][j], 0, 0, 0);
            }
    }
    // writeout: C layout col=lane&15, row=fq*4+reg
    #pragma unroll
    for (int i = 0; i < 2; ++i) {
        int grow0 = m0 + (w << 5) + i * 16 + (fq << 2);
        #pragma unroll
        for (int j = 0; j < 4; ++j) {
            int gn = j * 16 + fr;
            float* dst = (gn < 32) ? (qo + grow0 * DH + gn)
                                   : (ko + grow0 * DH + gn - 32);
            dst[0]      = acc[i][j][0];
            dst[DH]     = acc[i][j][1];
            dst[2 * DH] = acc[i][j][2];
            dst[3 * DH] = acc[i][j][3];
        }
    }
}

// ---------------- K2: hi-only bf16 MFMA sim GEMM + per-row top-12 per 128-col chunk
// Staging via global_load_lds, pre-swizzled source / swizzled ds_read (rule #21).
// Scan: 128 threads handle half-rows (64 cols), register-resident sorted insert;
// two sorted-12 lists merged with a 48-CAS bitonic network via LDS.
// Output: single u32 packed key per candidate: value[31:12] | (4095 - gidx).
__global__ __launch_bounds__(256, 4) void topk_mfma_kernel(
        const __bf16* __restrict__ xhi, unsigned* __restrict__ pkey)
{
    __shared__ __align__(16) float Sbuf[64 * 129];     // 33024 B; staging aliases
    __shared__ unsigned kbuf[128 * 13];                // 6656 B half-row key lists
    __bf16* stg = (__bf16*)Sbuf;
    // buf layout (bf16 units): A0 @0 (4096), B0 @4096, A1 @8192, B1 @12288

    int tid = threadIdx.x;
    int b = blockIdx.x / NBLK;
    int l = blockIdx.x - b * NBLK;
    int rt = (int)((sqrtf(8.f * l + 1.f) - 1.f) * 0.5f);
    while ((rt + 1) * (rt + 2) / 2 <= l) ++rt;
    while (rt * (rt + 1) / 2 > l) --rt;
    int ct = l - rt * (rt + 1) / 2;
    int r0 = rt << 7, c0 = ct << 7;
    int base = b * T;

    int w = tid >> 6, lane = tid & 63;
    int wr = (w >> 1) << 6, wc = (w & 1) << 6;
    bool active = !(rt == ct && w == 1);   // diag block, fully non-causal quadrant
    int fr = lane & 15, fq = lane >> 4;    // fragment: row-in-tile, k-quad
    int fqs = (fq ^ ((fr >> 1) & 3)) << 3; // swizzled 16B-slot (bf16 offset)

    // staging: lane i of wave w covers (row 16w + (i>>2), swizzled 16B-chunk)
    int lrow = lane >> 2;
    int lcq = (((lane & 3) ^ ((lane >> 3) & 3)) << 3);   // pre-swizzled source slot
    const __bf16* gA = xhi + (size_t)(base + r0) * D;
    const __bf16* gB = xhi + (size_t)(base + c0) * D;
    const __bf16* gA0 = gA + (size_t)((w << 4) + lrow) * D + lcq;
    const __bf16* gA1 = gA0 + (size_t)64 * D;
    const __bf16* gB0 = gB + (size_t)((w << 4) + lrow) * D + lcq;
    const __bf16* gB1 = gB0 + (size_t)64 * D;

    f32x4 acc[4][4];
    #pragma unroll
    for (int i = 0; i < 4; ++i)
        #pragma unroll
        for (int j = 0; j < 4; ++j) acc[i][j] = (f32x4){0.f, 0.f, 0.f, 0.f};

    // issue tile 0 into buf0
    {
        __bf16* bA = stg;           // buf0
        __bf16* bB = stg + 4096;
        __builtin_amdgcn_global_load_lds((const AS1 unsigned int*)(gA0),
            (AS3 unsigned int*)(bA + (w << 9)), 16, 0, 0);
        __builtin_amdgcn_global_load_lds((const AS1 unsigned int*)(gA1),
            (AS3 unsigned int*)(bA + 2048 + (w << 9)), 16, 0, 0);
        __builtin_amdgcn_global_load_lds((const AS1 unsigned int*)(gB0),
            (AS3 unsigned int*)(bB + (w << 9)), 16, 0, 0);
        __builtin_amdgcn_global_load_lds((const AS1 unsigned int*)(gB1),
            (AS3 unsigned int*)(bB + 2048 + (w << 9)), 16, 0, 0);
    }

    for (int kc = 0; kc < 32; ++kc) {
        __syncthreads();                   // tile kc resident in buf[kc&1]
        if (kc + 1 < 32) {                 // DMA tile kc+1 into the other buffer
            int ko = (kc + 1) << 5;
            __bf16* bA = stg + (((kc + 1) & 1) << 13);
            __bf16* bB = bA + 4096;
            __builtin_amdgcn_global_load_lds((const AS1 unsigned int*)(gA0 + ko),
                (AS3 unsigned int*)(bA + (w << 9)), 16, 0, 0);
            __builtin_amdgcn_global_load_lds((const AS1 unsigned int*)(gA1 + ko),
                (AS3 unsigned int*)(bA + 2048 + (w << 9)), 16, 0, 0);
            __builtin_amdgcn_global_load_lds((const AS1 unsigned int*)(gB0 + ko),
                (AS3 unsigned int*)(bB + (w << 9)), 16, 0, 0);
            __builtin_amdgcn_global_load_lds((const AS1 unsigned int*)(gB1 + ko),
                (AS3 unsigned int*)(bB + 2048 + (w << 9)), 16, 0, 0);
        }
        if (active) {
            const __bf16* cA = stg + ((kc & 1) << 13);
            const __bf16* cB = cA + 4096;
            bf16x8 ah[4], bh[4];
            #pragma unroll
            for (int i = 0; i < 4; ++i) {
                int ar = wr + i * 16 + fr;
                ah[i] = *(const bf16x8*)(cA + ar * 32 + fqs);
                int bc = wc + i * 16 + fr;
                bh[i] = *(const bf16x8*)(cB + bc * 32 + fqs);
            }
            #pragma unroll
            for (int i = 0; i < 4; ++i)
                #pragma unroll
                for (int j = 0; j < 4; ++j)
                    acc[i][j] = __builtin_amdgcn_mfma_f32_16x16x32_bf16(ah[i], bh[j], acc[i][j], 0, 0, 0);
        }
    }

    int cr = fq << 2, cc = fr;             // C layout: col=lane&15, row=fq*4+reg
    #pragma unroll
    for (int phase = 0; phase < 2; ++phase) {
        __syncthreads();                   // staging reads / prior merge done
        if ((w >> 1) == phase) {           // waves owning rows [phase*64, +64)
            #pragma unroll
            for (int i = 0; i < 4; ++i)
                #pragma unroll
                for (int j = 0; j < 4; ++j) {
                    float* sp = Sbuf + (i * 16 + cr) * 129 + wc + j * 16 + cc;
                    sp[0]       = acc[i][j][0];
                    sp[129]     = acc[i][j][1];
                    sp[2 * 129] = acc[i][j][2];
                    sp[3 * 129] = acc[i][j][3];
                }
        }
        __syncthreads();
        if (tid < 128) {                   // 2 threads/row: half-row scanners
            int row = tid & 63, half = tid >> 6;
            int gt = r0 + (phase << 6) + row;
            int cmax = gt - c0;
            if (cmax > 128) cmax = 128;
            if (cmax < 0) cmax = 0;
            int h0 = half << 6;
            int hmax = cmax < (h0 + 64) ? cmax : (h0 + 64);
            // sorted-desc packed keys: (mono(v) & ~127) | (127 - col); 0 invalid
            unsigned key[NK];
            #pragma unroll
            for (int i = 0; i < NK; ++i) key[i] = 0u;
            const float* Srow = Sbuf + row * 129;
            for (int cb = h0; cb < hmax; cb += 8) {
                float v[8];
                #pragma unroll
                for (int j = 0; j < 8; ++j) v[j] = Srow[cb + j];   // 8 loads in flight
                #pragma unroll
                for (int j = 0; j < 8; ++j) {
                    int c = cb + j;
                    unsigned u = mono32(v[j]);
                    unsigned tk = (c < hmax) ? ((u & 0xFFFFFF80u) | (unsigned)(127 - c)) : 0u;
                    #pragma unroll
                    for (int i = 0; i < NK; ++i) {      // branchless sorted insert
                        unsigned hi = key[i] > tk ? key[i] : tk;
                        unsigned lo = key[i] > tk ? tk : key[i];
                        key[i] = hi; tk = lo;
                    }
                }
            }
            #pragma unroll
            for (int i = 0; i < NK; ++i) kbuf[tid * 13 + i] = key[i];
        }
        __syncthreads();
        if (tid < 64) {                    // bitonic merge of the two sorted lists
            unsigned a16[16], b16[16];
            #pragma unroll
            for (int i = 0; i < NK; ++i) {
                a16[i] = kbuf[tid * 13 + i];
                b16[i] = kbuf[(tid + 64) * 13 + i];
            }
            #pragma unroll
            for (int i = NK; i < 16; ++i) { a16[i] = 0u; b16[i] = 0u; }
            unsigned m16[16];
            #pragma unroll
            for (int i = 0; i < 16; ++i) {          // bitonic split, keep top-16
                unsigned aa = a16[i], bb = b16[15 - i];
                m16[i] = aa > bb ? aa : bb;
            }
            #pragma unroll
            for (int g = 8; g >= 1; g >>= 1) {      // bitonic merge, descending
                #pragma unroll
                for (int i = 0; i < 16; ++i) {
                    if (!(i & g)) {
                        unsigned x0 = m16[i], x1 = m16[i + g];
                        m16[i]     = x0 > x1 ? x0 : x1;
                        m16[i + g] = x0 > x1 ? x1 : x0;
                    }
                }
            }
            int gt = r0 + (phase << 6) + tid;
            int ob = (base + gt) * CPR + ct * NK;
            #pragma unroll
            for (int i = 0; i < NK; ++i) {          // repack: value20 | (4095-gidx)
                unsigned kk = m16[i];
                int gcol = c0 + 127 - (int)(kk & 127u);
                pkey[ob + i] = kk ? ((kk & 0xFFFFF000u) | (unsigned)(4095 - gcol)) : 0u;
            }
        }
    }
}

// ---------------- K3: FUSED wave-per-row selection + message + gelu ----------
// u32 packed-key candidates; 12 DPP extract-max passes (winners wave-uniform
// in SGPRs); scalar-addressed exact re-rank with DPP sum reduce; u64 exact
// top-8 insert; DPP 8-group score reduce. No LDS, no scratch, no bpermute.
__global__ __launch_bounds__(256) void select_msg_kernel(const float* __restrict__ x,
        const float* __restrict__ q, const float* __restrict__ k,
        const float* __restrict__ meansum,
        const unsigned* __restrict__ pkey,
        const float* __restrict__ gain, const float* __restrict__ bias,
        const float* __restrict__ plm, const float* __restrict__ pls,
        float* __restrict__ out)
{
    int tid = threadIdx.x;
    int w = tid >> 6, lane = tid & 63;
    int rid = (blockIdx.x << 2) + w;         // global row b*T+t
    int b = rid >> 12, t = rid & (T - 1);
    int ncand = NK * ((t + 127) >> 7);

    // candidate loads (all in flight)
    unsigned cv[6];
    #pragma unroll
    for (int u = 0; u < 6; ++u) {
        int cid = lane + (u << 6);
        cv[u] = (cid < ncand) ? pkey[(size_t)rid * CPR + cid] : 0u;
    }
    // prefetch xt fragments (independent of merge)
    const float* xt = x + (size_t)rid * D;
    float4 xt4[4];
    #pragma unroll
    for (int c = 0; c < 4; ++c)
        xt4[c] = *(const float4*)(xt + (c << 8) + (lane << 2));

    // 12 DPP extract-max passes -> wave-uniform winners (keys unique: idx in key)
    unsigned skey[NK]; int sgid[NK];
    #pragma unroll
    for (int i = 0; i < NK; ++i) {
        unsigned m = cv[0];
        #pragma unroll
        for (int u = 1; u < 6; ++u) m = m > cv[u] ? m : cv[u];
        m = dpp_umax_bcast(m);               // uniform (SGPR)
        skey[i] = m;
        sgid[i] = 4095 - (int)(m & 4095u);
        #pragma unroll
        for (int u = 0; u < 6; ++u) cv[u] = (cv[u] == m) ? 0u : cv[u];
    }

    // exact fp32 re-rank: 3 batches of 4; uniform row bases, DPP sum reduce
    float ex[NK];
    #pragma unroll
    for (int batch = 0; batch < 3; ++batch) {
        float4 rv[4][4];
        #pragma unroll
        for (int s = 0; s < 4; ++s) {
            int i = batch * 4 + s;
            int row = (skey[i] != 0u) ? sgid[i] : 0;
            const float* xj = x + (size_t)((b << 12) + row) * D;
            #pragma unroll
            for (int c = 0; c < 4; ++c)
                rv[s][c] = *(const float4*)(xj + (c << 8) + (lane << 2));
        }
        #pragma unroll
        for (int s = 0; s < 4; ++s) {
            float ss = 0.f;
            #pragma unroll
            for (int c = 0; c < 4; ++c)
                ss += xt4[c].x * rv[s][c].x + xt4[c].y * rv[s][c].y
                    + xt4[c].z * rv[s][c].z + xt4[c].w * rv[s][c].w;
            ex[batch * 4 + s] = dpp_fsum_bcast(ss);   // uniform
        }
    }

    // exact top-8 via u64 packed keys: (mono(value) << 12) | (4095 - idx)
    unsigned long long top8[8];
    #pragma unroll
    for (int r = 0; r < 8; ++r) top8[r] = 0ull;
    #pragma unroll
    for (int i = 0; i < NK; ++i) {
        unsigned u = mono32(ex[i]);
        unsigned long long t64 = (skey[i] != 0u)
            ? ((((unsigned long long)u) << 12) | (unsigned long long)(4095 - sgid[i]))
            : 0ull;
        #pragma unroll
        for (int r = 0; r < 8; ++r) {       // branchless sorted insert
            unsigned long long hi = (t64 > top8[r]) ? t64 : top8[r];
            unsigned long long lo = (t64 > top8[r]) ? top8[r] : t64;
            top8[r] = hi; t64 = lo;
        }
    }
    bool vld[8]; int bidx[8];
    #pragma unroll
    for (int i = 0; i < 8; ++i) {
        vld[i]  = top8[i] != 0ull;
        bidx[i] = 4095 - (int)(top8[i] & 4095ull);
    }

    // scores: lanes 8i..8i+7 compute dot(q[t], k[sel_i]); key via cndmask tree
    int i8 = lane >> 3, e = lane & 7;
    unsigned long long kk = (i8 & 4)
        ? ((i8 & 2) ? ((i8 & 1) ? top8[7] : top8[6]) : ((i8 & 1) ? top8[5] : top8[4]))
        : ((i8 & 2) ? ((i8 & 1) ? top8[3] : top8[2]) : ((i8 & 1) ? top8[1] : top8[0]));
    bool v8 = kk != 0ull;
    int g8 = v8 ? (4095 - (int)(kk & 4095ull)) : 0;
    float4 qv = *(const float4*)(q + (size_t)rid * DH + (e << 2));
    float4 kv = *(const float4*)(k + (size_t)((b << 12) + g8) * DH + (e << 2));
    float p = qv.x * kv.x + qv.y * kv.y + qv.z * kv.z + qv.w * kv.w;
    p = dpp_gsum8(p);
    p *= 0.17677669529663687f;               // 1/sqrt(32)

    float sc[8];
    #pragma unroll
    for (int i = 0; i < 8; ++i)
        sc[i] = __int_as_float(__builtin_amdgcn_readlane(__float_as_int(p), i << 3));

    float m = -INFINITY; int cnt = 0;
    #pragma unroll
    for (int i = 0; i < 8; ++i)
        if (vld[i]) { ++cnt; if (sc[i] > m) m = sc[i]; }

    float wgt[8]; float Z = 0.f; int gsel[8];
    #pragma unroll
    for (int i = 0; i < 8; ++i) {
        wgt[i] = vld[i] ? expf(sc[i] - m) : 0.f;
        Z += wgt[i];
        gsel[i] = vld[i] ? ((b << 12) + bidx[i]) : (b << 12);
    }
    float invZ = (cnt > 0) ? 1.f / Z : 0.f;
    #pragma unroll
    for (int i = 0; i < 8; ++i) wgt[i] *= invZ;

    // ---- fused epilogue: msg accumulation on lane's 16 dims + gelu ----
    float mix   = 1.f / (1.f + expf(-plm[0]));
    float scale = log1pf(expf(pls[0])) + 0.01f;
    const float onemix = 1.f - mix;

    float4 msg4[4];
    if (cnt == 0) {                          // t==0: uniform attention over ALL T
        #pragma unroll
        for (int c = 0; c < 4; ++c) {
            float4 ms = *(const float4*)(meansum + (b << 10) + (c << 8) + (lane << 2));
            msg4[c].x = ms.x * (1.f / (float)T); msg4[c].y = ms.y * (1.f / (float)T);
            msg4[c].z = ms.z * (1.f / (float)T); msg4[c].w = ms.w * (1.f / (float)T);
        }
    } else {
        #pragma unroll
        for (int c = 0; c < 4; ++c) msg4[c] = (float4){0.f, 0.f, 0.f, 0.f};
        #pragma unroll
        for (int g = 0; g < 2; ++g) {        // 2 batches of 4 rows (L2-hot re-read)
            float4 rv[4][4];
            #pragma unroll
            for (int s = 0; s < 4; ++s) {
                const float* xj = x + (size_t)gsel[g * 4 + s] * D;
                #pragma unroll
                for (int c = 0; c < 4; ++c)
                    rv[s][c] = *(const float4*)(xj + (c << 8) + (lane << 2));
            }
            #pragma unroll
            for (int s = 0; s < 4; ++s) {    // preserves i=0..7 summation order
                float wi = wgt[g * 4 + s];
                #pragma unroll
                for (int c = 0; c < 4; ++c) {
                    msg4[c].x += wi * rv[s][c].x; msg4[c].y += wi * rv[s][c].y;
                    msg4[c].z += wi * rv[s][c].z; msg4[c].w += wi * rv[s][c].w;
                }
            }
        }
    }
    #pragma unroll
    for (int c = 0; c < 4; ++c) {
        int d0 = (c << 8) + (lane << 2);
        float4 g4 = *(const float4*)(gain + d0);
        float4 b4 = *(const float4*)(bias + d0);
        float4 xv = xt4[c];
        float zi[4] = {
            (mix * xv.x + onemix * msg4[c].x) * g4.x + b4.x,
            (mix * xv.y + onemix * msg4[c].y) * g4.y + b4.y,
            (mix * xv.z + onemix * msg4[c].z) * g4.z + b4.z,
            (mix * xv.w + onemix * msg4[c].w) * g4.w + b4.w };
        float4 o4;
        o4.x = 0.5f * zi[0] * (1.f + erff(zi[0] * 0.70710678118654752f)) * scale;
        o4.y = 0.5f * zi[1] * (1.f + erff(zi[1] * 0.70710678118654752f)) * scale;
        o4.z = 0.5f * zi[2] * (1.f + erff(zi[2] * 0.70710678118654752f)) * scale;
        o4.w = 0.5f * zi[3] * (1.f + erff(zi[3] * 0.70710678118654752f)) * scale;
        *(float4*)(out + (size_t)rid * D + d0) = o4;
    }
}

extern "C" void kernel_launch(void* const* d_in, const int* in_sizes, int n_in,
                              void* d_out, int out_size, void* d_ws, size_t ws_size,
                              hipStream_t stream)
{
    const float* x    = (const float*)d_in[0];
    const float* Wq   = (const float*)d_in[1];
    const float* Wk   = (const float*)d_in[2];
    const float* gain = (const float*)d_in[3];
    const float* bias = (const float*)d_in[4];
    const float* plm  = (const float*)d_in[5];
    const float* pls  = (const float*)d_in[6];
    float* out = (float*)d_out;

    float* ws      = (float*)d_ws;
    float* q       = ws;                       // 262144
    float* k       = ws + 262144;              // 262144
    float* meansum = ws + 524288;              // 2048
    unsigned* pkey = (unsigned*)(ws + 526336); // B*T*CPR u32 = 3145728 slots
    __bf16* xhi    = (__bf16*)(ws + 3672064);  // B*T*D bf16 (4194304 float-slots)
    __bf16* xlo    = xhi + (size_t)B * T * D;
    __bf16* Whi    = xlo + (size_t)B * T * D;  // 64*1024 bf16
    __bf16* Wlo    = Whi + 64 * D;
    // total ws use: ~49 MB

    hipMemsetAsync(meansum, 0, 2048 * sizeof(float), stream);
    conv_kernel<<<B * T * D / 2048, 256, 0, stream>>>(x, xhi, xlo);
    conv_kernel<<<16, 256, 0, stream>>>(Wq, Whi, Wlo);
    conv_kernel<<<16, 256, 0, stream>>>(Wk, Whi + 32 * D, Wlo + 32 * D);
    mean_kernel<<<128, 256, 0, stream>>>(x, meansum);
    qk_mfma_kernel<<<B * T / 128, 256, 0, stream>>>(xhi, xlo, Whi, Wlo, q, k);
    topk_mfma_kernel<<<B * NBLK, 256, 0, stream>>>(xhi, pkey);
    select_msg_kernel<<<B * T / 4, 256, 0, stream>>>(x, q, k, meansum, pkey,
                                                     gain, bias, plm, pls, out);
}

// Round 4
// 267.487 us; speedup vs baseline: 1.4900x; 1.0623x over previous
//
#include <hip/hip_runtime.h>
#include <math.h>

#define B 2
#define T 4096
#define D 1024
#define DH 32
#define TNB 32        // 128-row tiles per batch
#define NBLK 528      // TNB*(TNB+1)/2 causal tile pairs
#define NK 12         // per-chunk candidates kept (safety margin over 8)
#define CPR (32*NK)   // candidates per row = 384

typedef __bf16 bf16x8 __attribute__((ext_vector_type(8)));
typedef float f32x4 __attribute__((ext_vector_type(4)));

#define AS1 __attribute__((address_space(1)))
#define AS3 __attribute__((address_space(3)))

// monotone f32 -> u32 (order-preserving); branchless
__device__ __forceinline__ unsigned mono32(float v) {
    unsigned u = __float_as_uint(v);
    u ^= ((unsigned)((int)u >> 31)) | 0x80000000u;
    return u;
}

// ---- wave-wide u32 max, result broadcast via readlane(63) (uniform/SGPR) ----
__device__ __forceinline__ unsigned dpp_umax_bcast(unsigned v) {
    #define DPPMAX(CTRL) { unsigned t_ = (unsigned)__builtin_amdgcn_update_dpp(0, (int)v, CTRL, 0xF, 0xF, true); v = v > t_ ? v : t_; }
    DPPMAX(0x111) DPPMAX(0x112) DPPMAX(0x114) DPPMAX(0x118)   // row_shr 1,2,4,8
    DPPMAX(0x142) DPPMAX(0x143)                               // row_bcast 15,31
    #undef DPPMAX
    return (unsigned)__builtin_amdgcn_readlane((int)v, 63);
}
// ---- wave-wide f32 sum, result broadcast via readlane(63) (uniform/SGPR) ----
__device__ __forceinline__ float dpp_fsum_bcast(float v) {
    #define DPPADD(CTRL) { int t_ = __builtin_amdgcn_update_dpp(0, __float_as_int(v), CTRL, 0xF, 0xF, true); v += __int_as_float(t_); }
    DPPADD(0x111) DPPADD(0x112) DPPADD(0x114) DPPADD(0x118)
    DPPADD(0x142) DPPADD(0x143)
    #undef DPPADD
    return __int_as_float(__builtin_amdgcn_readlane(__float_as_int(v), 63));
}
// ---- sum across each aligned 8-lane group (all lanes get the sum) ----
__device__ __forceinline__ float dpp_gsum8(float p) {
    { int t_ = __builtin_amdgcn_update_dpp(0, __float_as_int(p), 0x0B1, 0xF, 0xF, true); p += __int_as_float(t_); } // quad_perm xor1
    { int t_ = __builtin_amdgcn_update_dpp(0, __float_as_int(p), 0x04E, 0xF, 0xF, true); p += __int_as_float(t_); } // quad_perm xor2
    { int t_ = __builtin_amdgcn_update_dpp(0, __float_as_int(p), 0x141, 0xF, 0xF, true); p += __int_as_float(t_); } // row_half_mirror (xor7)
    return p;
}

// ---- bitonic merge of two sorted-desc 12-lists (packed unique keys) ----
__device__ __forceinline__ void merge12(const unsigned* a12, const unsigned* b12,
                                        unsigned* o12) {
    unsigned m16[16];
    #pragma unroll
    for (int i = 0; i < 16; ++i) {          // bitonic split, keep top-16
        unsigned aa = (i < NK) ? a12[i] : 0u;
        unsigned bb = (15 - i < NK) ? b12[15 - i] : 0u;
        m16[i] = aa > bb ? aa : bb;
    }
    #pragma unroll
    for (int g = 8; g >= 1; g >>= 1) {      // bitonic merge, descending
        #pragma unroll
        for (int i = 0; i < 16; ++i) {
            if (!(i & g)) {
                unsigned x0 = m16[i], x1 = m16[i + g];
                m16[i]     = x0 > x1 ? x0 : x1;
                m16[i + g] = x0 > x1 ? x1 : x0;
            }
        }
    }
    #pragma unroll
    for (int i = 0; i < NK; ++i) o12[i] = m16[i];
}

// ---------------- K_conv: src -> (hi, lo) bf16 split (2048 elems/block) -------
__global__ __launch_bounds__(256) void conv_kernel(const float* __restrict__ x,
        __bf16* __restrict__ xhi, __bf16* __restrict__ xlo)
{
    int i = (blockIdx.x * 256 + threadIdx.x) << 3;     // 8 floats/thread
    float4 a = *(const float4*)(x + i);
    float4 c = *(const float4*)(x + i + 4);
    float av[8] = {a.x, a.y, a.z, a.w, c.x, c.y, c.z, c.w};
    __bf16 h[8], l[8];
    #pragma unroll
    for (int j = 0; j < 8; ++j) {
        h[j] = (__bf16)av[j];
        l[j] = (__bf16)(av[j] - (float)h[j]);
    }
    *(float4*)(xhi + i) = *(float4*)h;
    *(float4*)(xlo + i) = *(float4*)l;
}

// ---------------- K0: per-batch column sums (for the t=0 row) ----------------
__global__ void mean_kernel(const float* __restrict__ x, float* __restrict__ meansum)
{
    int gid  = blockIdx.x;           // B * 4 dblk * 16 tch = 128 blocks
    int b    = gid >> 6;
    int rem  = gid & 63;
    int dblk = rem >> 4;
    int tch  = rem & 15;
    int d = dblk * 256 + threadIdx.x;
    const float* xp = x + (b * T + tch * 256) * D + d;
    float s = 0.f;
    #pragma unroll 8
    for (int it = 0; it < 256; ++it) s += xp[it * D];
    atomicAdd(&meansum[(b << 10) + d], s);
}

// ---------------- K1: q/k projection, split-bf16 MFMA, 64-row blocks ---------
__global__ __launch_bounds__(256) void qk_mfma_kernel(
        const __bf16* __restrict__ xhi, const __bf16* __restrict__ xlo,
        const __bf16* __restrict__ Whi, const __bf16* __restrict__ Wlo,
        float* __restrict__ qo, float* __restrict__ ko)
{
    __shared__ __align__(16) __bf16 stg[10240];
    __bf16* sAhi = stg;            // 64 x 40
    __bf16* sAlo = stg + 2560;
    __bf16* sBhi = stg + 5120;     // 64 x 40
    __bf16* sBlo = stg + 7680;

    int tid = threadIdx.x;
    int m0 = blockIdx.x << 6;
    int w = tid >> 6, lane = tid & 63;
    int fr = lane & 15, fq = lane >> 4;

    int arow = tid >> 2, aq = tid & 3;      // 4 chunks of 8 bf16 per row
    const __bf16* gAh = xhi + (size_t)(m0 + arow) * D + aq * 8;
    const __bf16* gAl = xlo + (size_t)(m0 + arow) * D + aq * 8;
    const __bf16* gBh = Whi + arow * D + aq * 8;
    const __bf16* gBl = Wlo + arow * D + aq * 8;

    f32x4 acc[4];
    #pragma unroll
    for (int j = 0; j < 4; ++j) acc[j] = (f32x4){0.f, 0.f, 0.f, 0.f};

    float4 a0 = *(const float4*)(gAh);
    float4 a1 = *(const float4*)(gAl);
    float4 b0 = *(const float4*)(gBh);
    float4 b1 = *(const float4*)(gBl);

    int sa = arow * 40 + aq * 8;

    for (int kc = 0; kc < 32; ++kc) {
        __syncthreads();
        *(float4*)(sAhi + sa) = a0;
        *(float4*)(sAlo + sa) = a1;
        *(float4*)(sBhi + sa) = b0;
        *(float4*)(sBlo + sa) = b1;
        __syncthreads();
        if (kc + 1 < 32) {
            int k0 = (kc + 1) << 5;
            a0 = *(const float4*)(gAh + k0);
            a1 = *(const float4*)(gAl + k0);
            b0 = *(const float4*)(gBh + k0);
            b1 = *(const float4*)(gBl + k0);
        }
        int r = (w << 4) + fr;
        bf16x8 fah = *(const bf16x8*)(sAhi + r * 40 + fq * 8);
        bf16x8 fal = *(const bf16x8*)(sAlo + r * 40 + fq * 8);
        bf16x8 fbh[4], fbl[4];
        #pragma unroll
        for (int j = 0; j < 4; ++j) {
            int rb = j * 16 + fr;
            fbh[j] = *(const bf16x8*)(sBhi + rb * 40 + fq * 8);
            fbl[j] = *(const bf16x8*)(sBlo + rb * 40 + fq * 8);
        }
        #pragma unroll
        for (int j = 0; j < 4; ++j) {
            acc[j] = __builtin_amdgcn_mfma_f32_16x16x32_bf16(fah, fbh[j], acc[j], 0, 0, 0);
            acc[j] = __builtin_amdgcn_mfma_f32_16x16x32_bf16(fah, fbl[j], acc[j], 0, 0, 0);
            acc[j] = __builtin_amdgcn_mfma_f32_16x16x32_bf16(fal, fbh[j], acc[j], 0, 0, 0);
        }
    }
    // writeout: C layout col=lane&15, row=fq*4+reg
    int grow0 = m0 + (w << 4) + (fq << 2);
    #pragma unroll
    for (int j = 0; j < 4; ++j) {
        int gn = j * 16 + fr;
        float* dst = (gn < 32) ? (qo + grow0 * DH + gn)
                               : (ko + grow0 * DH + gn - 32);
        dst[0]      = acc[j][0];
        dst[DH]     = acc[j][1];
        dst[2 * DH] = acc[j][2];
        dst[3 * DH] = acc[j][3];
    }
}

// ---------------- K2: hi-only bf16 MFMA sim GEMM + per-row top-12 per 128-col chunk
// Triple-buffered global_load_lds with COUNTED vmcnt(4) + raw s_barrier: the
// next tile's 4 loads stay in flight across the barrier (T4), giving each
// tile ~2 iterations of latency cover. Scan: 256 threads quarter-scan 32 cols
// each, then 2-level bitonic merge of sorted-12 key lists (keys unique per
// col, merge-order independent). Output: value[31:12] | (4095 - gidx).
__global__ __launch_bounds__(256, 4) void topk_mfma_kernel(
        const __bf16* __restrict__ xhi, unsigned* __restrict__ pkey)
{
    __shared__ __align__(16) char smem[49152];
    __bf16* stg = (__bf16*)smem;           // 3 bufs x 16384 B (A 8KB | B 8KB)
    float* Sbuf = (float*)smem;            // 64 x 129 fp32 = 33024 B (post-loop)
    unsigned* kbuf = (unsigned*)(smem + 33024);   // 256 x 13 u32 = 13312 B

    int tid = threadIdx.x;
    int b = blockIdx.x / NBLK;
    int l = blockIdx.x - b * NBLK;
    int rt = (int)((sqrtf(8.f * l + 1.f) - 1.f) * 0.5f);
    while ((rt + 1) * (rt + 2) / 2 <= l) ++rt;
    while (rt * (rt + 1) / 2 > l) --rt;
    int ct = l - rt * (rt + 1) / 2;
    int r0 = rt << 7, c0 = ct << 7;
    int base = b * T;

    int w = tid >> 6, lane = tid & 63;
    int wr = (w >> 1) << 6, wc = (w & 1) << 6;
    bool active = !(rt == ct && w == 1);   // diag block, fully non-causal quadrant
    int fr = lane & 15, fq = lane >> 4;    // fragment: row-in-tile, k-quad
    int fqs = (fq ^ ((fr >> 1) & 3)) << 3; // swizzled 16B-slot (bf16 offset)

    // staging: lane i of wave w covers (row 16w + (i>>2), swizzled 16B-chunk)
    int lrow = lane >> 2;
    int lcq = (((lane & 3) ^ ((lane >> 3) & 3)) << 3);   // pre-swizzled source slot
    const __bf16* gA = xhi + (size_t)(base + r0) * D;
    const __bf16* gB = xhi + (size_t)(base + c0) * D;
    const __bf16* gA0 = gA + (size_t)((w << 4) + lrow) * D + lcq;
    const __bf16* gA1 = gA0 + (size_t)64 * D;
    const __bf16* gB0 = gB + (size_t)((w << 4) + lrow) * D + lcq;
    const __bf16* gB1 = gB0 + (size_t)64 * D;

    f32x4 acc[4][4];
    #pragma unroll
    for (int i = 0; i < 4; ++i)
        #pragma unroll
        for (int j = 0; j < 4; ++j) acc[i][j] = (f32x4){0.f, 0.f, 0.f, 0.f};

#define ISSUE_TILE(BUFBASE, KO) do { \
    __bf16* bA_ = (BUFBASE); \
    __bf16* bB_ = bA_ + 4096; \
    __builtin_amdgcn_global_load_lds((const AS1 unsigned int*)(gA0 + (KO)), \
        (AS3 unsigned int*)(bA_ + (w << 9)), 16, 0, 0); \
    __builtin_amdgcn_global_load_lds((const AS1 unsigned int*)(gA1 + (KO)), \
        (AS3 unsigned int*)(bA_ + 2048 + (w << 9)), 16, 0, 0); \
    __builtin_amdgcn_global_load_lds((const AS1 unsigned int*)(gB0 + (KO)), \
        (AS3 unsigned int*)(bB_ + (w << 9)), 16, 0, 0); \
    __builtin_amdgcn_global_load_lds((const AS1 unsigned int*)(gB1 + (KO)), \
        (AS3 unsigned int*)(bB_ + 2048 + (w << 9)), 16, 0, 0); \
} while (0)

    // prologue: tiles 0 and 1 in flight
    ISSUE_TILE(stg, 0);
    ISSUE_TILE(stg + 8192, 32);

    int bsel = 0, isel = 2;
    for (int kc = 0; kc < 32; ++kc) {
        // wait for tile kc only: the newest 4 loads (tile kc+1) stay in flight
        if (kc < 31) { asm volatile("s_waitcnt vmcnt(4)" ::: "memory"); }
        else         { asm volatile("s_waitcnt vmcnt(0)" ::: "memory"); }
        __builtin_amdgcn_s_barrier();
        asm volatile("" ::: "memory");
        if (kc + 2 < 32) {                 // DMA tile kc+2 (reuses tile kc-1 buf:
            ISSUE_TILE(stg + isel * 8192, (kc + 2) << 5);  // its reads finished
            isel = (isel == 2) ? 0 : isel + 1;             // before this barrier)
        }
        if (active) {
            const __bf16* cA = stg + bsel * 8192;
            const __bf16* cB = cA + 4096;
            bf16x8 ah[4], bh[4];
            #pragma unroll
            for (int i = 0; i < 4; ++i) {
                int ar = wr + i * 16 + fr;
                ah[i] = *(const bf16x8*)(cA + ar * 32 + fqs);
                int bc = wc + i * 16 + fr;
                bh[i] = *(const bf16x8*)(cB + bc * 32 + fqs);
            }
            #pragma unroll
            for (int i = 0; i < 4; ++i)
                #pragma unroll
                for (int j = 0; j < 4; ++j)
                    acc[i][j] = __builtin_amdgcn_mfma_f32_16x16x32_bf16(ah[i], bh[j], acc[i][j], 0, 0, 0);
        }
        bsel = (bsel == 2) ? 0 : bsel + 1;
    }
#undef ISSUE_TILE

    int cr = fq << 2, cc = fr;             // C layout: col=lane&15, row=fq*4+reg
    #pragma unroll
    for (int phase = 0; phase < 2; ++phase) {
        __syncthreads();                   // staging reads / prior phase done
        if ((w >> 1) == phase) {           // waves owning rows [phase*64, +64)
            #pragma unroll
            for (int i = 0; i < 4; ++i)
                #pragma unroll
                for (int j = 0; j < 4; ++j) {
                    float* sp = Sbuf + (i * 16 + cr) * 129 + wc + j * 16 + cc;
                    sp[0]       = acc[i][j][0];
                    sp[129]     = acc[i][j][1];
                    sp[2 * 129] = acc[i][j][2];
                    sp[3 * 129] = acc[i][j][3];
                }
        }
        __syncthreads();
        // stage 1: 256 threads, 4 per row, 32-col quarter scans
        {
            int row = tid & 63, qtr = tid >> 6;
            int gt = r0 + (phase << 6) + row;
            int cmax = gt - c0;
            if (cmax > 128) cmax = 128;
            if (cmax < 0) cmax = 0;
            int h0 = qtr << 5;
            int hmax = cmax < (h0 + 32) ? cmax : (h0 + 32);
            unsigned key[NK];
            #pragma unroll
            for (int i = 0; i < NK; ++i) key[i] = 0u;
            const float* Srow = Sbuf + row * 129;
            for (int cb = h0; cb < hmax; cb += 8) {
                float v[8];
                #pragma unroll
                for (int j = 0; j < 8; ++j) v[j] = Srow[cb + j];   // 8 in flight
                #pragma unroll
                for (int j = 0; j < 8; ++j) {
                    int c = cb + j;
                    unsigned u = mono32(v[j]);
                    unsigned tk = (c < hmax) ? ((u & 0xFFFFFF80u) | (unsigned)(127 - c)) : 0u;
                    #pragma unroll
                    for (int i = 0; i < NK; ++i) {      // branchless sorted insert
                        unsigned hi = key[i] > tk ? key[i] : tk;
                        unsigned lo = key[i] > tk ? tk : key[i];
                        key[i] = hi; tk = lo;
                    }
                }
            }
            #pragma unroll
            for (int i = 0; i < NK; ++i) kbuf[tid * 13 + i] = key[i];
        }
        __syncthreads();
        if (tid < 128) {                   // stage 2: merge quarter pairs
            int r = tid & 63, hf = tid >> 6;
            int ia = r + (hf << 7);        // lists (r + 128*hf), (r + 128*hf + 64)
            unsigned a12[NK], b12[NK], o12[NK];
            #pragma unroll
            for (int i = 0; i < NK; ++i) {
                a12[i] = kbuf[ia * 13 + i];
                b12[i] = kbuf[(ia + 64) * 13 + i];
            }
            merge12(a12, b12, o12);
            #pragma unroll
            for (int i = 0; i < NK; ++i) kbuf[ia * 13 + i] = o12[i];
        }
        __syncthreads();
        if (tid < 64) {                    // stage 3: final merge + store
            unsigned a12[NK], b12[NK], o12[NK];
            #pragma unroll
            for (int i = 0; i < NK; ++i) {
                a12[i] = kbuf[tid * 13 + i];
                b12[i] = kbuf[(tid + 128) * 13 + i];
            }
            merge12(a12, b12, o12);
            int gt = r0 + (phase << 6) + tid;
            int ob = (base + gt) * CPR + ct * NK;
            #pragma unroll
            for (int i = 0; i < NK; ++i) {          // repack: value20 | (4095-gidx)
                unsigned kk = o12[i];
                int gcol = c0 + 127 - (int)(kk & 127u);
                pkey[ob + i] = kk ? ((kk & 0xFFFFF000u) | (unsigned)(4095 - gcol)) : 0u;
            }
        }
    }
}

// ---------------- K3: FUSED wave-per-row selection + message + gelu ----------
// u32 packed-key candidates; 12 DPP extract-max passes (winners wave-uniform
// in SGPRs); scalar-addressed exact re-rank with DPP sum reduce; u64 exact
// top-8 insert; DPP 8-group score reduce. No LDS, no scratch, no bpermute.
__global__ __launch_bounds__(256) void select_msg_kernel(const float* __restrict__ x,
        const float* __restrict__ q, const float* __restrict__ k,
        const float* __restrict__ meansum,
        const unsigned* __restrict__ pkey,
        const float* __restrict__ gain, const float* __restrict__ bias,
        const float* __restrict__ plm, const float* __restrict__ pls,
        float* __restrict__ out)
{
    int tid = threadIdx.x;
    int w = tid >> 6, lane = tid & 63;
    int rid = (blockIdx.x << 2) + w;         // global row b*T+t
    int b = rid >> 12, t = rid & (T - 1);
    int ncand = NK * ((t + 127) >> 7);

    // candidate loads (all in flight)
    unsigned cv[6];
    #pragma unroll
    for (int u = 0; u < 6; ++u) {
        int cid = lane + (u << 6);
        cv[u] = (cid < ncand) ? pkey[(size_t)rid * CPR + cid] : 0u;
    }
    // prefetch xt fragments (independent of merge)
    const float* xt = x + (size_t)rid * D;
    float4 xt4[4];
    #pragma unroll
    for (int c = 0; c < 4; ++c)
        xt4[c] = *(const float4*)(xt + (c << 8) + (lane << 2));

    // 12 DPP extract-max passes -> wave-uniform winners (keys unique: idx in key)
    unsigned skey[NK]; int sgid[NK];
    #pragma unroll
    for (int i = 0; i < NK; ++i) {
        unsigned m = cv[0];
        #pragma unroll
        for (int u = 1; u < 6; ++u) m = m > cv[u] ? m : cv[u];
        m = dpp_umax_bcast(m);               // uniform (SGPR)
        skey[i] = m;
        sgid[i] = 4095 - (int)(m & 4095u);
        #pragma unroll
        for (int u = 0; u < 6; ++u) cv[u] = (cv[u] == m) ? 0u : cv[u];
    }

    // exact fp32 re-rank: 3 batches of 4; uniform row bases, DPP sum reduce
    float ex[NK];
    #pragma unroll
    for (int batch = 0; batch < 3; ++batch) {
        float4 rv[4][4];
        #pragma unroll
        for (int s = 0; s < 4; ++s) {
            int i = batch * 4 + s;
            int row = (skey[i] != 0u) ? sgid[i] : 0;
            const float* xj = x + (size_t)((b << 12) + row) * D;
            #pragma unroll
            for (int c = 0; c < 4; ++c)
                rv[s][c] = *(const float4*)(xj + (c << 8) + (lane << 2));
        }
        #pragma unroll
        for (int s = 0; s < 4; ++s) {
            float ss = 0.f;
            #pragma unroll
            for (int c = 0; c < 4; ++c)
                ss += xt4[c].x * rv[s][c].x + xt4[c].y * rv[s][c].y
                    + xt4[c].z * rv[s][c].z + xt4[c].w * rv[s][c].w;
            ex[batch * 4 + s] = dpp_fsum_bcast(ss);   // uniform
        }
    }

    // exact top-8 via u64 packed keys: (mono(value) << 12) | (4095 - idx)
    unsigned long long top8[8];
    #pragma unroll
    for (int r = 0; r < 8; ++r) top8[r] = 0ull;
    #pragma unroll
    for (int i = 0; i < NK; ++i) {
        unsigned u = mono32(ex[i]);
        unsigned long long t64 = (skey[i] != 0u)
            ? ((((unsigned long long)u) << 12) | (unsigned long long)(4095 - sgid[i]))
            : 0ull;
        #pragma unroll
        for (int r = 0; r < 8; ++r) {       // branchless sorted insert
            unsigned long long hi = (t64 > top8[r]) ? t64 : top8[r];
            unsigned long long lo = (t64 > top8[r]) ? top8[r] : t64;
            top8[r] = hi; t64 = lo;
        }
    }
    bool vld[8]; int bidx[8];
    #pragma unroll
    for (int i = 0; i < 8; ++i) {
        vld[i]  = top8[i] != 0ull;
        bidx[i] = 4095 - (int)(top8[i] & 4095ull);
    }

    // scores: lanes 8i..8i+7 compute dot(q[t], k[sel_i]); key via cndmask tree
    int i8 = lane >> 3, e = lane & 7;
    unsigned long long kk = (i8 & 4)
        ? ((i8 & 2) ? ((i8 & 1) ? top8[7] : top8[6]) : ((i8 & 1) ? top8[5] : top8[4]))
        : ((i8 & 2) ? ((i8 & 1) ? top8[3] : top8[2]) : ((i8 & 1) ? top8[1] : top8[0]));
    bool v8 = kk != 0ull;
    int g8 = v8 ? (4095 - (int)(kk & 4095ull)) : 0;
    float4 qv = *(const float4*)(q + (size_t)rid * DH + (e << 2));
    float4 kv = *(const float4*)(k + (size_t)((b << 12) + g8) * DH + (e << 2));
    float p = qv.x * kv.x + qv.y * kv.y + qv.z * kv.z + qv.w * kv.w;
    p = dpp_gsum8(p);
    p *= 0.17677669529663687f;               // 1/sqrt(32)

    float sc[8];
    #pragma unroll
    for (int i = 0; i < 8; ++i)
        sc[i] = __int_as_float(__builtin_amdgcn_readlane(__float_as_int(p), i << 3));

    float m = -INFINITY; int cnt = 0;
    #pragma unroll
    for (int i = 0; i < 8; ++i)
        if (vld[i]) { ++cnt; if (sc[i] > m) m = sc[i]; }

    float wgt[8]; float Z = 0.f; int gsel[8];
    #pragma unroll
    for (int i = 0; i < 8; ++i) {
        wgt[i] = vld[i] ? expf(sc[i] - m) : 0.f;
        Z += wgt[i];
        gsel[i] = vld[i] ? ((b << 12) + bidx[i]) : (b << 12);
    }
    float invZ = (cnt > 0) ? 1.f / Z : 0.f;
    #pragma unroll
    for (int i = 0; i < 8; ++i) wgt[i] *= invZ;

    // ---- fused epilogue: msg accumulation on lane's 16 dims + gelu ----
    float mix   = 1.f / (1.f + expf(-plm[0]));
    float scale = log1pf(expf(pls[0])) + 0.01f;
    const float onemix = 1.f - mix;

    float4 msg4[4];
    if (cnt == 0) {                          // t==0: uniform attention over ALL T
        #pragma unroll
        for (int c = 0; c < 4; ++c) {
            float4 ms = *(const float4*)(meansum + (b << 10) + (c << 8) + (lane << 2));
            msg4[c].x = ms.x * (1.f / (float)T); msg4[c].y = ms.y * (1.f / (float)T);
            msg4[c].z = ms.z * (1.f / (float)T); msg4[c].w = ms.w * (1.f / (float)T);
        }
    } else {
        #pragma unroll
        for (int c = 0; c < 4; ++c) msg4[c] = (float4){0.f, 0.f, 0.f, 0.f};
        #pragma unroll
        for (int g = 0; g < 2; ++g) {        // 2 batches of 4 rows (L2-hot re-read)
            float4 rv[4][4];
            #pragma unroll
            for (int s = 0; s < 4; ++s) {
                const float* xj = x + (size_t)gsel[g * 4 + s] * D;
                #pragma unroll
                for (int c = 0; c < 4; ++c)
                    rv[s][c] = *(const float4*)(xj + (c << 8) + (lane << 2));
            }
            #pragma unroll
            for (int s = 0; s < 4; ++s) {    // preserves i=0..7 summation order
                float wi = wgt[g * 4 + s];
                #pragma unroll
                for (int c = 0; c < 4; ++c) {
                    msg4[c].x += wi * rv[s][c].x; msg4[c].y += wi * rv[s][c].y;
                    msg4[c].z += wi * rv[s][c].z; msg4[c].w += wi * rv[s][c].w;
                }
            }
        }
    }
    #pragma unroll
    for (int c = 0; c < 4; ++c) {
        int d0 = (c << 8) + (lane << 2);
        float4 g4 = *(const float4*)(gain + d0);
        float4 b4 = *(const float4*)(bias + d0);
        float4 xv = xt4[c];
        float zi[4] = {
            (mix * xv.x + onemix * msg4[c].x) * g4.x + b4.x,
            (mix * xv.y + onemix * msg4[c].y) * g4.y + b4.y,
            (mix * xv.z + onemix * msg4[c].z) * g4.z + b4.z,
            (mix * xv.w + onemix * msg4[c].w) * g4.w + b4.w };
        float4 o4;
        o4.x = 0.5f * zi[0] * (1.f + erff(zi[0] * 0.70710678118654752f)) * scale;
        o4.y = 0.5f * zi[1] * (1.f + erff(zi[1] * 0.70710678118654752f)) * scale;
        o4.z = 0.5f * zi[2] * (1.f + erff(zi[2] * 0.70710678118654752f)) * scale;
        o4.w = 0.5f * zi[3] * (1.f + erff(zi[3] * 0.70710678118654752f)) * scale;
        *(float4*)(out + (size_t)rid * D + d0) = o4;
    }
}

extern "C" void kernel_launch(void* const* d_in, const int* in_sizes, int n_in,
                              void* d_out, int out_size, void* d_ws, size_t ws_size,
                              hipStream_t stream)
{
    const float* x    = (const float*)d_in[0];
    const float* Wq   = (const float*)d_in[1];
    const float* Wk   = (const float*)d_in[2];
    const float* gain = (const float*)d_in[3];
    const float* bias = (const float*)d_in[4];
    const float* plm  = (const float*)d_in[5];
    const float* pls  = (const float*)d_in[6];
    float* out = (float*)d_out;

    float* ws      = (float*)d_ws;
    float* q       = ws;                       // 262144
    float* k       = ws + 262144;              // 262144
    float* meansum = ws + 524288;              // 2048
    unsigned* pkey = (unsigned*)(ws + 526336); // B*T*CPR u32 = 3145728 slots
    __bf16* xhi    = (__bf16*)(ws + 3672064);  // B*T*D bf16 (4194304 float-slots)
    __bf16* xlo    = xhi + (size_t)B * T * D;
    __bf16* Whi    = xlo + (size_t)B * T * D;  // 64*1024 bf16
    __bf16* Wlo    = Whi + 64 * D;
    // total ws use: ~49 MB

    hipMemsetAsync(meansum, 0, 2048 * sizeof(float), stream);
    conv_kernel<<<B * T * D / 2048, 256, 0, stream>>>(x, xhi, xlo);
    conv_kernel<<<16, 256, 0, stream>>>(Wq, Whi, Wlo);
    conv_kernel<<<16, 256, 0, stream>>>(Wk, Whi + 32 * D, Wlo + 32 * D);
    mean_kernel<<<128, 256, 0, stream>>>(x, meansum);
    qk_mfma_kernel<<<B * T / 64, 256, 0, stream>>>(xhi, xlo, Whi, Wlo, q, k);
    topk_mfma_kernel<<<B * NBLK, 256, 0, stream>>>(xhi, pkey);
    select_msg_kernel<<<B * T / 4, 256, 0, stream>>>(x, q, k, meansum, pkey,
                                                     gain, bias, plm, pls, out);
}